// Round 10
// baseline (246.115 us; speedup 1.0000x reference)
//
#include <hip/hip_runtime.h>
#include <stdint.h>

#define NEG_SLOPE 0.2f
#define EPSV 1e-16f
#define LOG2E 1.44269504088896340736f
#define NBLK 256   // scatter/histogram blocks (fixed, deterministic edge ranges)

typedef __attribute__((ext_vector_type(8))) short short8;
typedef __attribute__((ext_vector_type(4))) float f32x4;

// round-to-nearest-even fp32 -> bf16 bits
__device__ inline short bf16r(float f){
  union { float f; unsigned u; } v; v.f = f;
  unsigned r = (v.u + 0x7FFFu + ((v.u >> 16) & 1u)) >> 16;
  return (short)r;
}
__device__ inline float bf16lo(unsigned u){
  union { unsigned u; float f; } v; v.u = u << 16; return v.f;
}
__device__ inline float bf16hi(unsigned u){
  union { unsigned u; float f; } v; v.u = u & 0xFFFF0000u; return v.f;
}

// ---------------- edge access (int32 or int64 edge_index, [2,E] row-major) ----------------
__device__ inline void get_edge(const void* ei, int is64, int E, int e, int& s, int& d){
  if (e >= E){ s = d = e - E; return; }  // self loops appended
  if (is64){
    const long long* p = (const long long*)ei;
    s = (int)p[e]; d = (int)p[(long long)E + e];
  } else {
    const int* p = (const int*)ei;
    s = p[e]; d = p[E + e];
  }
}

__device__ inline int get_dst(const void* ei, int is64, int E, int e){
  if (e >= E) return e - E;
  if (is64) return (int)((const long long*)ei)[(long long)E + e];
  return ((const int*)ei)[E + e];
}

// ---------------- prep: detect dtype + pack W1/W2 + gemv att2 (one kernel) ----------------
__device__ inline void pack_one(const float* W, short* Wp, int NCOL, int idx){
  int NNT = NCOL >> 4;
  int j = idx & 7, n16 = (idx >> 3) & 15, q = (idx >> 7) & 3, tile = idx >> 9;
  int nt = tile % NNT, kt = tile / NNT;
  int k = kt*32 + q*8 + j, n = nt*16 + n16;
  Wp[idx] = bf16r(W[k*NCOL + n]);
}
__global__ void prep(const int* __restrict__ ei32, int* __restrict__ flag,
                     const float* __restrict__ W1, short* __restrict__ W1p,
                     const float* __restrict__ W2, short* __restrict__ W2p,
                     const float* __restrict__ as2, const float* __restrict__ ad2,
                     float* __restrict__ va_s, float* __restrict__ va_d){
  int b = blockIdx.x, t = threadIdx.x;
  if (b < 64){
    int idx = b*256 + t;                 // 16384 total
    if (idx < 8192) pack_one(W1, W1p, 64, idx);
    else            pack_one(W2, W2p, 128, idx - 8192);
  } else {
    if (t == 0){
      int nz = 0;
      for (int i = 0; i < 64; ++i) nz |= ei32[2*i + 1];  // int64: high words all 0
      *flag = (nz == 0) ? 1 : 0;
    }
    if (t < 64){
      float s = 0.f, d = 0.f;
      for (int c = 0; c < 128; ++c){
        float w = W2[t*128 + c];
        s = fmaf(w, as2[c], s);
        d = fmaf(w, ad2[c], d);
      }
      va_s[t] = s * LOG2E; va_d[t] = d * LOG2E;   // pre-scaled for exp2
    }
  }
}

// ---------------- GEMM1 (fp32 x input, bf16 out) + fused layer-1 logits (x LOG2E) ----------------
__global__ __launch_bounds__(256) void gemm1(const float* __restrict__ x, const short* __restrict__ Bp,
                                             const float* __restrict__ att_s, const float* __restrict__ att_d,
                                             short* __restrict__ Cb,
                                             float* __restrict__ asrc1, float* __restrict__ adst1, int M){
  constexpr int NKT = 4, NNT = 4;      // K=128, NCOL=64
  int wave = (blockIdx.x*256 + (int)threadIdx.x) >> 6;
  int lane = threadIdx.x & 63;
  int row0 = wave << 4;
  if (row0 >= M) return;
  int m = lane & 15, q = lane >> 4;
  f32x4 acc[NNT];
#pragma unroll
  for (int i = 0; i < NNT; ++i) acc[i] = (f32x4){0.f,0.f,0.f,0.f};
#pragma unroll
  for (int kt = 0; kt < NKT; ++kt){
    const float* xr = x + (size_t)(row0 + m)*128 + kt*32 + q*8;
    f32x4 f0 = *(const f32x4*)xr;
    f32x4 f1 = *(const f32x4*)(xr + 4);
    short8 a;
#pragma unroll
    for (int j = 0; j < 4; ++j){ a[j] = bf16r(f0[j]); a[4 + j] = bf16r(f1[j]); }
#pragma unroll
    for (int nt = 0; nt < NNT; ++nt){
      short8 b = *(const short8*)(Bp + (size_t)(((kt*NNT + nt)*4 + q)*16 + m)*8);
      acc[nt] = __builtin_amdgcn_mfma_f32_16x16x32_bf16(a, b, acc[nt], 0, 0, 0);
    }
  }
  // store bf16 h1
#pragma unroll
  for (int nt = 0; nt < NNT; ++nt){
#pragma unroll
    for (int r = 0; r < 4; ++r){
      Cb[(size_t)(row0 + q*4 + r)*64 + nt*16 + m] = bf16r(acc[nt][r]);
    }
  }
  // fused logits: head = 2*nt + (m>>3); octet = m&7; scaled by LOG2E
  float atts[4], attd[4];
#pragma unroll
  for (int nt = 0; nt < 4; ++nt){
    atts[nt] = att_s[nt*16 + m] * LOG2E;
    attd[nt] = att_d[nt*16 + m] * LOG2E;
  }
  int isw = (m & 7) == 0;
#pragma unroll
  for (int r = 0; r < 4; ++r){
    int row = row0 + q*4 + r;
#pragma unroll
    for (int nt = 0; nt < 4; ++nt){
      float ps = acc[nt][r] * atts[nt];
      float pd = acc[nt][r] * attd[nt];
#pragma unroll
      for (int mm = 1; mm <= 4; mm <<= 1){
        ps += __shfl_xor(ps, mm, 64);
        pd += __shfl_xor(pd, mm, 64);
      }
      if (isw){
        int head = 2*nt + (m >> 3);
        asrc1[row*8 + head] = ps;
        adst1[row*8 + head] = pd;
      }
    }
  }
}

// ---------------- GEMM2 with bias, fp32 out (final layer) ----------------
__global__ __launch_bounds__(256) void gemm2(const short* __restrict__ A, const short* __restrict__ Bp,
                                             const float* __restrict__ bias,
                                             float* __restrict__ C, int M){
  constexpr int NKT = 2, NNT = 8;      // K=64, NCOL=128
  int wave = (blockIdx.x*256 + (int)threadIdx.x) >> 6;
  int lane = threadIdx.x & 63;
  int row0 = wave << 4;
  if (row0 >= M) return;
  int m = lane & 15, q = lane >> 4;
  f32x4 acc[NNT];
#pragma unroll
  for (int i = 0; i < NNT; ++i) acc[i] = (f32x4){0.f,0.f,0.f,0.f};
#pragma unroll
  for (int kt = 0; kt < NKT; ++kt){
    short8 a = *(const short8*)(A + (size_t)(row0 + m)*64 + kt*32 + q*8);
#pragma unroll
    for (int nt = 0; nt < NNT; ++nt){
      short8 b = *(const short8*)(Bp + (size_t)(((kt*NNT + nt)*4 + q)*16 + m)*8);
      acc[nt] = __builtin_amdgcn_mfma_f32_16x16x32_bf16(a, b, acc[nt], 0, 0, 0);
    }
  }
#pragma unroll
  for (int nt = 0; nt < NNT; ++nt){
    float bv = bias[nt*16 + m];
#pragma unroll
    for (int r = 0; r < 4; ++r){
      C[(size_t)(row0 + q*4 + r)*128 + nt*16 + m] = acc[nt][r] + bv;
    }
  }
}

// ================= CSR build: two-level counting sort (no global atomics) =================
__global__ __launch_bounds__(256) void p1_hist(const void* ei, const int* flag, int E, int E2,
                                               int* __restrict__ block_counts){
  __shared__ int h[256];
  int t = threadIdx.x, blk = blockIdx.x;
  h[t] = 0; __syncthreads();
  int chunk = (E2 + NBLK - 1)/NBLK;
  int beg = blk*chunk, end = min(beg + chunk, E2);
  int is64 = *flag;
  for (int e = beg + t; e < end; e += 256){
    int d = get_dst(ei, is64, E, e);
    atomicAdd(&h[d >> 8], 1);
  }
  __syncthreads();
  block_counts[blk*256 + t] = h[t];
}

// merged p2: grid=256 blocks, block b handles bucket b; block 0 also publishes bucket_base
__global__ __launch_bounds__(256) void p2_scan(const int* __restrict__ block_counts,
                                               int* __restrict__ bucket_base,
                                               int* __restrict__ block_off){
  __shared__ int tot[256];
  __shared__ int ex[256];
  __shared__ int col[256];
  int b = blockIdx.x, t = threadIdx.x;
  int s = 0;
  for (int w = 0; w < NBLK; ++w) s += block_counts[w*256 + t];
  tot[t] = s; __syncthreads();
  for (int off = 1; off < 256; off <<= 1){
    int v = (t >= off) ? tot[t - off] : 0;
    __syncthreads(); tot[t] += v; __syncthreads();
  }
  ex[t] = tot[t] - s;        // exclusive bucket base
  __syncthreads();
  if (b == 0){
    bucket_base[t] = ex[t];
    if (t == 255) bucket_base[256] = tot[255];
  }
  int base = ex[b];
  int v = block_counts[t*256 + b];
  col[t] = v; __syncthreads();
  for (int off = 1; off < 256; off <<= 1){
    int u = (t >= off) ? col[t - off] : 0;
    __syncthreads(); col[t] += u; __syncthreads();
  }
  block_off[t*256 + b] = base + col[t] - v;
}

// P3: scatter packed (s<<8 | d&255) into bucket-major runs (4 B/edge; s < 2^24, N=50000)
__global__ __launch_bounds__(256) void p3_scatter(const void* ei, const int* flag, int E, int E2,
                                                  const int* __restrict__ block_off,
                                                  unsigned* __restrict__ packed){
  __shared__ int cur[256];
  int t = threadIdx.x, blk = blockIdx.x;
  cur[t] = block_off[blk*256 + t];
  __syncthreads();
  int chunk = (E2 + NBLK - 1)/NBLK;
  int beg = blk*chunk, end = min(beg + chunk, E2);
  int is64 = *flag;
  for (int e = beg + t; e < end; e += 256){
    int s, d; get_edge(ei, is64, E, e, s, d);
    int pos = atomicAdd(&cur[d >> 8], 1);
    packed[pos] = ((unsigned)s << 8) | (unsigned)(d & 255);
  }
}

// P4: in-bucket counting sort; srcs stored as BYTE offsets (s*128) for 32-bit gather addressing
__global__ __launch_bounds__(256) void p4_sort(const unsigned* __restrict__ packed,
                                               const int* __restrict__ bucket_base,
                                               int N, int E2,
                                               int* __restrict__ offs, int* __restrict__ srcs){
  __shared__ int hist[256];
  __shared__ int cur[256];
  int b = blockIdx.x, t = threadIdx.x;
  int base = bucket_base[b], cnt = bucket_base[b + 1] - base;
  hist[t] = 0; __syncthreads();
  for (int p = t; p < cnt; p += 256){
    atomicAdd(&hist[packed[base + p] & 255u], 1);
  }
  __syncthreads();
  int v = hist[t];
  cur[t] = v; __syncthreads();
  for (int off = 1; off < 256; off <<= 1){
    int u = (t >= off) ? cur[t - off] : 0;
    __syncthreads(); cur[t] += u; __syncthreads();
  }
  int ex = cur[t] - v;   // exclusive prefix within bucket
  __syncthreads();
  cur[t] = ex;
  int node = b*256 + t;
  if (node < N) offs[node] = base + ex;
  __syncthreads();
  for (int p = t; p < cnt; p += 256){
    unsigned pk = packed[base + p];
    int pos = atomicAdd(&cur[pk & 255u], 1);
    srcs[base + pos] = (int)((pk >> 8) << 7);   // byte offset s*128
  }
  if (b == 0 && t == 0) offs[N] = E2;
}

// butterfly reduce-scatter over the 8 lane-groups: returns this lane's final column sum;
// col = c*8 + (b0*4 + b1*2 + b2), bits of g. (7 shfl vs 24 for all-reduce)
__device__ inline float rscatter8(float acc[8], int g){
  float r4[4];
  int b0 = g & 1;
#pragma unroll
  for (int j = 0; j < 4; ++j){
    float sel  = b0 ? acc[j]     : acc[j + 4];   // half partner keeps
    float keep = b0 ? acc[j + 4] : acc[j];       // half I keep
    r4[j] = keep + __shfl_xor(sel, 8, 64);
  }
  float r2[2];
  int b1 = (g >> 1) & 1;
#pragma unroll
  for (int j = 0; j < 2; ++j){
    float sel  = b1 ? r4[j]     : r4[j + 2];
    float keep = b1 ? r4[j + 2] : r4[j];
    r2[j] = keep + __shfl_xor(sel, 16, 64);
  }
  int b2 = (g >> 2) & 1;
  float sel  = b2 ? r2[0] : r2[1];
  float keep = b2 ? r2[1] : r2[0];
  return keep + __shfl_xor(sel, 32, 64);
}
__device__ inline int rscol(int g, int c){
  return c*8 + (g & 1)*4 + (g & 2) + ((g >> 2) & 1);
}

// ---------------- layer-1 aggregation + fused ELU + fused layer-2 logits ----------------
// logits pre-scaled by LOG2E -> weights via exp2f. srcs[] holds byte offsets (s*128).
// main loop: clamp-free 32-edge body; tail: 8-edge single-slot iterations.
__global__ __launch_bounds__(256) void agg_l1(const char* __restrict__ h1b,
                       const float* __restrict__ asrc, const float* __restrict__ adst,
                       const int* __restrict__ offs, const int* __restrict__ srcs,
                       const float* __restrict__ bias,
                       const float* __restrict__ va_s, const float* __restrict__ va_d,
                       unsigned short* __restrict__ hout,
                       float* __restrict__ asrc2, float* __restrict__ adst2, int N){
  int tid = threadIdx.x;
  int i = blockIdx.x*4 + (tid >> 6);
  if (i >= N) return;
  int lane = tid & 63, g = lane >> 3, c = lane & 7;
  unsigned coff = (unsigned)(c << 4);
  float ad = adst[i*8 + c];
  int beg = offs[i], end = offs[i + 1], last = end - 1;
  float acc[8];
#pragma unroll
  for (int k = 0; k < 8; ++k) acc[k] = 0.f;
  float den = 0.f;
  int p = beg;
  for (; p + 32 <= end; p += 32){
    unsigned so[4];
#pragma unroll
    for (int k = 0; k < 4; ++k) so[k] = (unsigned)srcs[p + 8*k + g];
    float a[4];
#pragma unroll
    for (int k = 0; k < 4; ++k) a[k] = asrc[(so[k] >> 4) + (unsigned)c];
    uint4 v[4];
#pragma unroll
    for (int k = 0; k < 4; ++k) v[k] = *(const uint4*)(h1b + (size_t)(so[k] + coff));
    float w[4];
#pragma unroll
    for (int k = 0; k < 4; ++k){
      float z = a[k] + ad;
      z = fmaxf(z, NEG_SLOPE*z);
      w[k] = exp2f(z);
      den += w[k];
    }
#pragma unroll
    for (int k = 0; k < 4; ++k){
      acc[0] = fmaf(w[k], bf16lo(v[k].x), acc[0]); acc[1] = fmaf(w[k], bf16hi(v[k].x), acc[1]);
      acc[2] = fmaf(w[k], bf16lo(v[k].y), acc[2]); acc[3] = fmaf(w[k], bf16hi(v[k].y), acc[3]);
      acc[4] = fmaf(w[k], bf16lo(v[k].z), acc[4]); acc[5] = fmaf(w[k], bf16hi(v[k].z), acc[5]);
      acc[6] = fmaf(w[k], bf16lo(v[k].w), acc[6]); acc[7] = fmaf(w[k], bf16hi(v[k].w), acc[7]);
    }
  }
  for (; p < end; p += 8){
    int m = p + g;
    unsigned so = (unsigned)srcs[min(m, last)];
    float a = asrc[(so >> 4) + (unsigned)c];
    uint4 v = *(const uint4*)(h1b + (size_t)(so + coff));
    float z = a + ad;
    z = fmaxf(z, NEG_SLOPE*z);
    float w = (m < end) ? exp2f(z) : 0.f;
    den += w;
    acc[0] = fmaf(w, bf16lo(v.x), acc[0]); acc[1] = fmaf(w, bf16hi(v.x), acc[1]);
    acc[2] = fmaf(w, bf16lo(v.y), acc[2]); acc[3] = fmaf(w, bf16hi(v.y), acc[3]);
    acc[4] = fmaf(w, bf16lo(v.z), acc[4]); acc[5] = fmaf(w, bf16hi(v.z), acc[5]);
    acc[6] = fmaf(w, bf16lo(v.w), acc[6]); acc[7] = fmaf(w, bf16hi(v.w), acc[7]);
  }
  float r = rscatter8(acc, g);
  den += __shfl_xor(den, 8, 64);
  den += __shfl_xor(den, 16, 64);
  den += __shfl_xor(den, 32, 64);
  int col = rscol(g, c);
  float o = r/(den + EPSV) + bias[col];
  o = (o > 0.f) ? o : (__expf(o) - 1.f);      // ELU fused (1 expf per lane)
  hout[(size_t)i*64 + col] = (unsigned short)bf16r(o);
  // fused layer-2 logits: full-wave dot products with va (pre-scaled by LOG2E)
  float ps = o * va_s[col];
  float pd = o * va_d[col];
#pragma unroll
  for (int mm = 1; mm <= 32; mm <<= 1){
    ps += __shfl_xor(ps, mm, 64);
    pd += __shfl_xor(pd, mm, 64);
  }
  if (lane == 0){ asrc2[i] = ps; adst2[i] = pd; }
}

// ---------------- layer-2 aggregation over hin2 (64 bf16 cols; GEMM applied AFTER) ----------------
__global__ __launch_bounds__(256) void agg_l2(const char* __restrict__ hin2,
                       const float* __restrict__ asrc, const float* __restrict__ adst,
                       const int* __restrict__ offs, const int* __restrict__ srcs,
                       unsigned short* __restrict__ qout, int N){
  int tid = threadIdx.x;
  int i = blockIdx.x*4 + (tid >> 6);
  if (i >= N) return;
  int lane = tid & 63, g = lane >> 3, c = lane & 7;
  unsigned coff = (unsigned)(c << 4);
  float ad = adst[i];
  int beg = offs[i], end = offs[i + 1], last = end - 1;
  float acc[8];
#pragma unroll
  for (int k = 0; k < 8; ++k) acc[k] = 0.f;
  float den = 0.f;
  int p = beg;
  for (; p + 32 <= end; p += 32){
    unsigned so[4];
#pragma unroll
    for (int k = 0; k < 4; ++k) so[k] = (unsigned)srcs[p + 8*k + g];
    float a[4];
#pragma unroll
    for (int k = 0; k < 4; ++k) a[k] = asrc[so[k] >> 7];
    uint4 v[4];
#pragma unroll
    for (int k = 0; k < 4; ++k) v[k] = *(const uint4*)(hin2 + (size_t)(so[k] + coff));
    float w[4];
#pragma unroll
    for (int k = 0; k < 4; ++k){
      float z = a[k] + ad;
      z = fmaxf(z, NEG_SLOPE*z);
      w[k] = exp2f(z);
      den += w[k];
    }
#pragma unroll
    for (int k = 0; k < 4; ++k){
      acc[0] = fmaf(w[k], bf16lo(v[k].x), acc[0]); acc[1] = fmaf(w[k], bf16hi(v[k].x), acc[1]);
      acc[2] = fmaf(w[k], bf16lo(v[k].y), acc[2]); acc[3] = fmaf(w[k], bf16hi(v[k].y), acc[3]);
      acc[4] = fmaf(w[k], bf16lo(v[k].z), acc[4]); acc[5] = fmaf(w[k], bf16hi(v[k].z), acc[5]);
      acc[6] = fmaf(w[k], bf16lo(v[k].w), acc[6]); acc[7] = fmaf(w[k], bf16hi(v[k].w), acc[7]);
    }
  }
  for (; p < end; p += 8){
    int m = p + g;
    unsigned so = (unsigned)srcs[min(m, last)];
    float a = asrc[so >> 7];
    uint4 v = *(const uint4*)(hin2 + (size_t)(so + coff));
    float z = a + ad;
    z = fmaxf(z, NEG_SLOPE*z);
    float w = (m < end) ? exp2f(z) : 0.f;
    den += w;
    acc[0] = fmaf(w, bf16lo(v.x), acc[0]); acc[1] = fmaf(w, bf16hi(v.x), acc[1]);
    acc[2] = fmaf(w, bf16lo(v.y), acc[2]); acc[3] = fmaf(w, bf16hi(v.y), acc[3]);
    acc[4] = fmaf(w, bf16lo(v.z), acc[4]); acc[5] = fmaf(w, bf16hi(v.z), acc[5]);
    acc[6] = fmaf(w, bf16lo(v.w), acc[6]); acc[7] = fmaf(w, bf16hi(v.w), acc[7]);
  }
  float r = rscatter8(acc, g);
  den += __shfl_xor(den, 8, 64);
  den += __shfl_xor(den, 16, 64);
  den += __shfl_xor(den, 32, 64);
  int col = rscol(g, c);
  qout[(size_t)i*64 + col] = (unsigned short)bf16r(r/(den + EPSV));
}

// ---------------- launch ----------------
extern "C" void kernel_launch(void* const* d_in, const int* in_sizes, int n_in,
                              void* d_out, int out_size, void* d_ws, size_t ws_size,
                              hipStream_t stream){
  const float* x   = (const float*)d_in[0];
  const void*  ei  = d_in[1];
  const float* W1  = (const float*)d_in[2];
  const float* as1 = (const float*)d_in[3];
  const float* ad1 = (const float*)d_in[4];
  const float* b1  = (const float*)d_in[5];
  const float* W2  = (const float*)d_in[6];
  const float* as2 = (const float*)d_in[7];
  const float* ad2 = (const float*)d_in[8];
  const float* b2  = (const float*)d_in[9];

  int N  = in_sizes[0] / 128;
  int E  = in_sizes[1] / 2;
  int E2 = E + N;
  int NB = (N + 255) >> 8;   // dst buckets of 256 nodes

  char* p = (char*)d_ws;
  auto alloc = [&](size_t bytes) -> void* {
    void* r = (void*)p;
    p += (bytes + 255) & ~(size_t)255;
    return r;
  };
  short*    W1p    = (short*)alloc((size_t)128*64*2);
  short*    W2p    = (short*)alloc((size_t)64*128*2);
  short*    h1b    = (short*)alloc((size_t)N*64*2);
  float*    asrc1  = (float*)alloc((size_t)N*8*4);
  float*    adst1  = (float*)alloc((size_t)N*8*4);
  short*    hin2   = (short*)alloc((size_t)N*64*2);
  short*    hq     = (short*)alloc((size_t)N*64*2);
  float*    asrc2  = (float*)alloc((size_t)N*4);
  float*    adst2  = (float*)alloc((size_t)N*4);
  float*    va_s2  = (float*)alloc(64*4);
  float*    va_d2  = (float*)alloc(64*4);
  int*      offs   = (int*)alloc((size_t)(N + 1)*4);
  int*      srcs   = (int*)alloc((size_t)E2*4);
  unsigned* packed = (unsigned*)alloc((size_t)E2*4);
  int*      bcnt   = (int*)alloc((size_t)NBLK*256*4);
  int*      boff   = (int*)alloc((size_t)NBLK*256*4);
  int*      bbase  = (int*)alloc(257*4);
  int*      flag   = (int*)alloc(4);

  dim3 B(256);
  prep<<<65, B, 0, stream>>>((const int*)ei, flag, W1, W1p, W2, W2p, as2, ad2, va_s2, va_d2);

  int nwav = (N + 15)/16;
  gemm1<<<(nwav + 3)/4, B, 0, stream>>>(x, W1p, as1, ad1, h1b, asrc1, adst1, N);

  // CSR by dst via two-level counting sort (reused by both layers)
  p1_hist<<<NBLK, B, 0, stream>>>(ei, flag, E, E2, bcnt);
  p2_scan<<<256, B, 0, stream>>>(bcnt, bbase, boff);
  p3_scatter<<<NBLK, B, 0, stream>>>(ei, flag, E, E2, boff, packed);
  p4_sort<<<NB, B, 0, stream>>>(packed, bbase, N, E2, offs, srcs);

  agg_l1<<<(N + 3)/4, B, 0, stream>>>((const char*)h1b, asrc1, adst1, offs, srcs, b1,
                                      va_s2, va_d2, (unsigned short*)hin2, asrc2, adst2, N);

  agg_l2<<<(N + 3)/4, B, 0, stream>>>((const char*)hin2, asrc2, adst2, offs, srcs,
                                      (unsigned short*)hq, N);

  gemm2<<<(nwav + 3)/4, B, 0, stream>>>(hq, W2p, b2, (float*)d_out, N);
}